// Round 1
// baseline (358.994 us; speedup 1.0000x reference)
//
#include <hip/hip_runtime.h>
#include <stdint.h>
#include <stddef.h>

typedef __attribute__((ext_vector_type(8))) short short8;
typedef __attribute__((ext_vector_type(4))) float floatx4;

#define CI 128
#define CO 128
#define SP 32768          // 32*32*32
#define BATCH 8
#define STYLED 512
#define KV 3456           // CI*27

__device__ __forceinline__ short f2bf(float f) {
    uint32_t u = __builtin_bit_cast(uint32_t, f);
    u = (u + 0x7FFFu + ((u >> 16) & 1u)) >> 16;
    return (short)(u & 0xFFFFu);
}

// style_m[b][i] = 1 + affine_b[i] + sum_d s[b][d]*affine_w[i][d]
__global__ void k_style(const float* __restrict__ s, const float* __restrict__ aw,
                        const float* __restrict__ ab, float* __restrict__ m) {
    __shared__ float ssh[STYLED];
    int b = blockIdx.x;
    int i = threadIdx.x;  // 128 threads
    for (int r = 0; r < STYLED / 128; ++r) ssh[r * 128 + i] = s[b * STYLED + r * 128 + i];
    __syncthreads();
    float acc = ab[i] + 1.0f;
    const float4* awr = (const float4*)(aw + (size_t)i * STYLED);
    for (int d4 = 0; d4 < STYLED / 4; ++d4) {
        float4 v = awr[d4];
        acc += v.x * ssh[d4 * 4] + v.y * ssh[d4 * 4 + 1] + v.z * ssh[d4 * 4 + 2] + v.w * ssh[d4 * 4 + 3];
    }
    m[b * CI + i] = acc;
}

// wmodT[b][k][o][i] = w[o][i][k] * m[b][i] * rsqrt(sum + 1e-8)
__global__ void k_wmod(const float* __restrict__ w, const float* __restrict__ m,
                       short* __restrict__ wt) {
    int b = blockIdx.x >> 7;
    int o = blockIdx.x & 127;
    int lane = threadIdx.x;   // 64 threads
    const float* wrow = w + (size_t)o * KV;
    const float* mrow = m + b * CI;
    float sum = 0.f;
    for (int e = lane; e < KV; e += 64) {
        int i = e / 27;
        float v = wrow[e] * mrow[i];
        sum += v * v;
    }
    #pragma unroll
    for (int off = 32; off >= 1; off >>= 1) sum += __shfl_xor(sum, off);
    float scale = 1.0f / sqrtf(sum + 1e-8f);
    for (int e = lane; e < KV; e += 64) {
        int i = e / 27;
        int k = e - i * 27;
        float v = wrow[e] * mrow[i] * scale;
        wt[(((size_t)(b * 27 + k) * CO + o) << 7) + i] = f2bf(v);
    }
}

// xT[b][z][y][w][i] (bf16) from x[b][i][z][y][w] (f32)
__global__ void k_xt(const float* __restrict__ x, short* __restrict__ xt) {
    __shared__ float t[128][33];
    int bid = blockIdx.x;            // 8192 = 8 * 1024
    int b = bid >> 10;
    int zy = bid & 1023;             // z*32 + y
    const float* src = x + (size_t)b * CI * SP + (size_t)zy * 32;
    int tid = threadIdx.x;           // 256
    int wlane = tid & 31, irow = tid >> 5;
    for (int it = 0; it < 16; ++it) {
        int i = it * 8 + irow;
        t[i][wlane] = src[(size_t)i * SP + wlane];
    }
    __syncthreads();
    short* dst = xt + ((size_t)(b * SP + zy * 32)) * CI;
    for (int it = 0; it < 2; ++it) {
        int idx = it * 256 + tid;
        int wv = idx >> 4, g = idx & 15;
        short8 v;
        #pragma unroll
        for (int j = 0; j < 8; ++j) v[j] = f2bf(t[g * 8 + j][wv]);
        *(short8*)(dst + (size_t)wv * CI + g * 8) = v;
    }
}

// Implicit-GEMM conv: block = (b, z, ytile of 4 rows); M=128 c_out, N=128 spatial.
__launch_bounds__(512, 1)
__global__ void k_conv(const short* __restrict__ xt, const short* __restrict__ wt,
                       const float* __restrict__ bias, float* __restrict__ out) {
    __shared__ short lds_x[612 * 40];        // 3z * 6y * 34w rows, 32ch + pad8
    __shared__ short lds_w[2][128 * 40];     // double-buffered [o][32ch + pad8]

    int bid = blockIdx.x;
    int b = bid & 7;                 // sample -> XCD affinity
    int t = bid >> 3;                // 0..255
    int z = t & 31;
    int y0 = (t >> 5) * 4;
    int tid = threadIdx.x;
    int lane = tid & 63;
    int wid = tid >> 6;
    int wm = wid & 3;                // o-tile: wm*32
    int wn = wid >> 2;               // sp-tile: wn*64
    int l15 = lane & 15;
    int lhi = lane >> 4;             // 0..3
    int i8 = lhi * 8;                // k-group within chunk

    floatx4 acc[2][4];
    #pragma unroll
    for (int a = 0; a < 2; ++a)
        #pragma unroll
        for (int c = 0; c < 4; ++c) acc[a][c] = (floatx4){0.f, 0.f, 0.f, 0.f};

    const short* wbase = wt + (size_t)b * 27 * CO * CI;
    int wo = tid >> 2, wq = tid & 3; // weight staging coords

    for (int c = 0; c < 4; ++c) {    // c_in chunks of 32
        __syncthreads();
        // stage x halo chunk
        for (int it = 0; it < 5; ++it) {
            int idx = it * 512 + tid;
            if (idx < 2448) {
                int h = idx >> 2, q = idx & 3;
                int zh = h / 204; int r = h - zh * 204;
                int yh = r / 34;  int wh = r - yh * 34;
                int zz = z + zh - 1, yy = y0 + yh - 1, ww = wh - 1;
                short8 v = {0, 0, 0, 0, 0, 0, 0, 0};
                if ((unsigned)zz < 32u && (unsigned)yy < 32u && (unsigned)ww < 32u) {
                    v = *(const short8*)(xt + ((size_t)(b * SP + zz * 1024 + yy * 32 + ww)) * CI + c * 32 + q * 8);
                }
                *(short8*)&lds_x[h * 40 + q * 8] = v;
            }
        }
        // stage tap 0 weights into buf0
        {
            short8 v = *(const short8*)(wbase + ((size_t)0 * CO + wo) * CI + c * 32 + wq * 8);
            *(short8*)&lds_w[0][wo * 40 + wq * 8] = v;
        }
        __syncthreads();

        for (int tap = 0; tap < 27; ++tap) {
            short8 wreg;
            if (tap < 26) {  // issue next tap's weight load early (latency hides under MFMA)
                wreg = *(const short8*)(wbase + ((size_t)(tap + 1) * CO + wo) * CI + c * 32 + wq * 8);
            }
            int cur = tap & 1;
            int kd = tap / 9, r9 = tap - kd * 9;
            int kh = r9 / 3, kw = r9 - kh * 3;

            short8 afr[2];
            #pragma unroll
            for (int mf = 0; mf < 2; ++mf)
                afr[mf] = *(const short8*)&lds_w[cur][(wm * 32 + mf * 16 + l15) * 40 + i8];

            #pragma unroll
            for (int nf = 0; nf < 4; ++nf) {
                int n = wn * 64 + nf * 16;
                int yi = n >> 5;
                int wl = (n & 31) + l15;
                int h = (kd * 6 + yi + kh) * 34 + wl + kw;
                short8 bfr = *(const short8*)&lds_x[h * 40 + i8];
                #pragma unroll
                for (int mf = 0; mf < 2; ++mf)
                    acc[mf][nf] = __builtin_amdgcn_mfma_f32_16x16x32_bf16(afr[mf], bfr, acc[mf][nf], 0, 0, 0);
            }

            if (tap < 26) {
                __syncthreads();                          // prev readers of buf cur^1 done
                *(short8*)&lds_w[cur ^ 1][wo * 40 + wq * 8] = wreg;
                __syncthreads();                          // writes visible for tap+1
            }
        }
    }

    // epilogue: D layout col=lane&15, row=(lane>>4)*4+j  [guide-verified]
    float bv[2][4];
    #pragma unroll
    for (int mf = 0; mf < 2; ++mf)
        #pragma unroll
        for (int j = 0; j < 4; ++j)
            bv[mf][j] = bias[wm * 32 + mf * 16 + lhi * 4 + j];

    #pragma unroll
    for (int mf = 0; mf < 2; ++mf) {
        int o = wm * 32 + mf * 16 + lhi * 4;
        #pragma unroll
        for (int nf = 0; nf < 4; ++nf) {
            int n = wn * 64 + nf * 16 + l15;
            int yy = y0 + (n >> 5);
            int ww = n & 31;
            size_t obase = ((size_t)(b * CO + o)) * SP + (size_t)z * 1024 + yy * 32 + ww;
            #pragma unroll
            for (int j = 0; j < 4; ++j)
                out[obase + (size_t)j * SP] = acc[mf][nf][j] + bv[mf][j];
        }
    }
}

extern "C" void kernel_launch(void* const* d_in, const int* in_sizes, int n_in,
                              void* d_out, int out_size, void* d_ws, size_t ws_size,
                              hipStream_t stream) {
    const float* x  = (const float*)d_in[0];
    const float* s  = (const float*)d_in[1];
    const float* w  = (const float*)d_in[2];
    const float* bb = (const float*)d_in[3];
    const float* aw = (const float*)d_in[4];
    const float* ab = (const float*)d_in[5];
    float* out = (float*)d_out;

    // workspace layout
    float* style_m = (float*)d_ws;                                    // 4 KB
    short* wmodT   = (short*)((char*)d_ws + 4096);                    // 8*27*128*128 bf16 = 7,077,888 B
    short* xT      = (short*)((char*)d_ws + 4096 + 7077888);          // 8*32768*128 bf16 = 67,108,864 B

    k_style<<<BATCH, 128, 0, stream>>>(s, aw, ab, style_m);
    k_wmod<<<BATCH * CO, 64, 0, stream>>>(w, style_m, wmodT);
    k_xt<<<BATCH * 1024, 256, 0, stream>>>(x, xT);
    k_conv<<<BATCH * 256, 512, 0, stream>>>(xT, wmodT, bb, out);
}

// Round 2
// 295.944 us; speedup vs baseline: 1.2130x; 1.2130x over previous
//
#include <hip/hip_runtime.h>
#include <stdint.h>
#include <stddef.h>

typedef __attribute__((ext_vector_type(8))) short short8;
typedef __attribute__((ext_vector_type(4))) float floatx4;

#define CI 128
#define CO 128
#define SP 32768          // 32*32*32
#define BATCH 8
#define STYLED 512
#define KV 3456           // CI*27

typedef __attribute__((address_space(1))) const void gvoid_t;
typedef __attribute__((address_space(3))) void lvoid_t;

__device__ __forceinline__ void gload16(const void* g, void* l) {
    __builtin_amdgcn_global_load_lds((gvoid_t*)g, (lvoid_t*)l, 16, 0, 0);
}

__device__ __forceinline__ short f2bf(float f) {
    uint32_t u = __builtin_bit_cast(uint32_t, f);
    u = (u + 0x7FFFu + ((u >> 16) & 1u)) >> 16;
    return (short)(u & 0xFFFFu);
}

// style_m[b][i] = 1 + affine_b[i] + sum_d s[b][d]*affine_w[i][d]
__global__ void k_style(const float* __restrict__ s, const float* __restrict__ aw,
                        const float* __restrict__ ab, float* __restrict__ m) {
    __shared__ float ssh[STYLED];
    int b = blockIdx.x;
    int i = threadIdx.x;  // 128 threads
    for (int r = 0; r < STYLED / 128; ++r) ssh[r * 128 + i] = s[b * STYLED + r * 128 + i];
    __syncthreads();
    float acc = ab[i] + 1.0f;
    const float4* awr = (const float4*)(aw + (size_t)i * STYLED);
    for (int d4 = 0; d4 < STYLED / 4; ++d4) {
        float4 v = awr[d4];
        acc += v.x * ssh[d4 * 4] + v.y * ssh[d4 * 4 + 1] + v.z * ssh[d4 * 4 + 2] + v.w * ssh[d4 * 4 + 3];
    }
    m[b * CI + i] = acc;
}

// wmodT[b][c][tap][o][32] pre-swizzled: logical (o, granule g) stored at granule g ^ ((o>>1)&3)
__global__ void k_wmod(const float* __restrict__ w, const float* __restrict__ m,
                       short* __restrict__ wt) {
    int b = blockIdx.x >> 7;
    int o = blockIdx.x & 127;
    int lane = threadIdx.x;   // 64 threads
    const float* wrow = w + (size_t)o * KV;
    const float* mrow = m + b * CI;
    float sum = 0.f;
    for (int e = lane; e < KV; e += 64) {
        int i = e / 27;
        float v = wrow[e] * mrow[i];
        sum += v * v;
    }
    #pragma unroll
    for (int off = 32; off >= 1; off >>= 1) sum += __shfl_xor(sum, off);
    float scale = 1.0f / sqrtf(sum + 1e-8f);
    int ophase = (o >> 1) & 3;
    for (int e = lane; e < KV; e += 64) {
        int i = e / 27;
        int k = e - i * 27;
        float v = wrow[e] * mrow[i] * scale;
        int c = i >> 5, il = i & 31, g = il >> 3, r = il & 7;
        int gl = g ^ ophase;
        wt[(((size_t)((b * 4 + c) * 27 + k)) * 128 + o) * 32 + gl * 8 + r] = f2bf(v);
    }
}

// xT[b][z][y][w][i] (bf16) from x[b][i][z][y][w] (f32)
__global__ void k_xt(const float* __restrict__ x, short* __restrict__ xt) {
    __shared__ float t[128][33];
    int bid = blockIdx.x;            // 8192 = 8 * 1024
    int b = bid >> 10;
    int zy = bid & 1023;             // z*32 + y
    const float* src = x + (size_t)b * CI * SP + (size_t)zy * 32;
    int tid = threadIdx.x;           // 256
    int wlane = tid & 31, irow = tid >> 5;
    for (int it = 0; it < 16; ++it) {
        int i = it * 8 + irow;
        t[i][wlane] = src[(size_t)i * SP + wlane];
    }
    __syncthreads();
    short* dst = xt + ((size_t)(b * SP + zy * 32)) * CI;
    for (int it = 0; it < 2; ++it) {
        int idx = it * 256 + tid;
        int wv = idx >> 4, g = idx & 15;
        short8 v;
        #pragma unroll
        for (int j = 0; j < 8; ++j) v[j] = f2bf(t[g * 8 + j][wv]);
        *(short8*)(dst + (size_t)wv * CI + g * 8) = v;
    }
}

// Implicit-GEMM conv. Block = (b, ztile(2), ytile(4)); M=128 c_out, N=256 spatial.
// 8 waves as 2M x 4N, wave tile 64x64. LDS: x halo 4z*6y*34w rows of 32ch (64B,
// granule-swizzled), weights double-buffered 2x8KB (pre-swizzled in wmodT).
__launch_bounds__(512, 4)
__global__ void k_conv(const short* __restrict__ xt, const short* __restrict__ wt,
                       const float* __restrict__ bias, float* __restrict__ out,
                       const short* __restrict__ zeropage) {
    __shared__ short lds_x[816 * 32];     // 52224 B, linear rows of 64B
    __shared__ short lds_w[2][128 * 32];  // 2 x 8192 B

    int bid = blockIdx.x;
    int b = bid & 7;                 // sample -> XCD affinity
    int t = bid >> 3;                // 0..127
    int zt = t & 15, yt = t >> 4;
    int z0 = zt * 2, y0 = yt * 4;

    int tid = threadIdx.x;
    int lane = tid & 63;
    int wid = tid >> 6;
    int wm = wid >> 2;               // 0..1 : o-tile base wm*64
    int wn = wid & 3;                // 0..3 : spatial tile base wn*64
    int l15 = lane & 15;
    int lhi = lane >> 4;

    floatx4 acc[4][4];
    #pragma unroll
    for (int a = 0; a < 4; ++a)
        #pragma unroll
        for (int c = 0; c < 4; ++c) acc[a][c] = (floatx4){0.f, 0.f, 0.f, 0.f};

    const short* wb = wt + (size_t)b * (4 * 27 * 128 * 32);
    const short* xb = xt + (size_t)b * SP * CI;

    for (int c = 0; c < 4; ++c) {    // c_in chunks of 32
        // ---- stage x halo chunk: 816 rows * 4 granules = 51 wave-issues ----
        for (int j = 0; ; ++j) {
            int s = wid + 8 * j;
            if (s >= 51) break;
            int G = s * 64 + lane;
            int rowid = G >> 2, g = G & 3;
            int zh = rowid / 204; int rr = rowid - zh * 204;
            int yh = rr / 34;     int wh = rr - yh * 34;
            int zz = z0 + zh - 1, yy = y0 + yh - 1, ww = wh - 1;
            int q = g ^ ((rowid >> 1) & 3);          // source pre-swizzle
            const short* src;
            if ((unsigned)zz < 32u && (unsigned)yy < 32u && (unsigned)ww < 32u)
                src = xb + ((size_t)(zz * 1024 + yy * 32 + ww)) * CI + c * 32 + q * 8;
            else
                src = zeropage + q * 8;
            gload16(src, (void*)((char*)lds_x + s * 1024));
        }
        // ---- stage tap 0 weights into buf0 (wmodT already swizzled; linear copy) ----
        gload16(wb + ((size_t)(c * 27 + 0)) * 4096 + wid * 512 + lane * 8,
                (void*)((char*)lds_w[0] + wid * 1024));
        __syncthreads();

        for (int tap = 0; tap < 27; ++tap) {
            int cur = tap & 1;
            if (tap < 26)            // issue next tap's stage before compute
                gload16(wb + ((size_t)(c * 27 + tap + 1)) * 4096 + wid * 512 + lane * 8,
                        (void*)((char*)lds_w[cur ^ 1] + wid * 1024));
            int kd = tap / 9, r9 = tap - kd * 9;
            int kh = r9 / 3, kw = r9 - kh * 3;

            short8 af[4];
            #pragma unroll
            for (int mf = 0; mf < 4; ++mf) {
                int o = wm * 64 + mf * 16 + l15;
                af[mf] = *(const short8*)((const char*)lds_w[cur] + o * 64 +
                                          ((lhi ^ ((o >> 1) & 3)) << 4));
            }
            #pragma unroll
            for (int nf = 0; nf < 4; ++nf) {
                int n = wn * 64 + nf * 16;
                int zi = n >> 7, yi = (n >> 5) & 3;
                int h = ((zi + kd) * 6 + (yi + kh)) * 34 + (n & 31) + kw + l15;
                short8 bf = *(const short8*)((const char*)lds_x + h * 64 +
                                             ((lhi ^ ((h >> 1) & 3)) << 4));
                #pragma unroll
                for (int mf = 0; mf < 4; ++mf)
                    acc[mf][nf] = __builtin_amdgcn_mfma_f32_16x16x32_bf16(af[mf], bf, acc[mf][nf], 0, 0, 0);
            }
            __syncthreads();         // one barrier per tap: publishes next stage, retires reads
        }
    }

    // epilogue: D layout col=lane&15 (spatial), row=(lane>>4)*4+j (c_out)
    float bv[4][4];
    #pragma unroll
    for (int mf = 0; mf < 4; ++mf)
        #pragma unroll
        for (int j = 0; j < 4; ++j)
            bv[mf][j] = bias[wm * 64 + mf * 16 + lhi * 4 + j];

    #pragma unroll
    for (int mf = 0; mf < 4; ++mf) {
        int o = wm * 64 + mf * 16 + lhi * 4;
        #pragma unroll
        for (int nf = 0; nf < 4; ++nf) {
            int n = wn * 64 + nf * 16;
            int zi = n >> 7, yi = (n >> 5) & 3, wcol = (n & 31) + l15;
            size_t obase = ((size_t)(b * CO + o)) * SP + (size_t)(z0 + zi) * 1024 + (y0 + yi) * 32 + wcol;
            #pragma unroll
            for (int j = 0; j < 4; ++j)
                out[obase + (size_t)j * SP] = acc[mf][nf][j] + bv[mf][j];
        }
    }
}

extern "C" void kernel_launch(void* const* d_in, const int* in_sizes, int n_in,
                              void* d_out, int out_size, void* d_ws, size_t ws_size,
                              hipStream_t stream) {
    const float* x  = (const float*)d_in[0];
    const float* s  = (const float*)d_in[1];
    const float* w  = (const float*)d_in[2];
    const float* bb = (const float*)d_in[3];
    const float* aw = (const float*)d_in[4];
    const float* ab = (const float*)d_in[5];
    float* out = (float*)d_out;

    // workspace layout
    float* style_m = (float*)d_ws;                                    // 4 KB
    short* wmodT   = (short*)((char*)d_ws + 4096);                    // 8*4*27*128*32 bf16 = 7,077,888 B
    short* xT      = (short*)((char*)d_ws + 4096 + 7077888);          // 8*32768*128 bf16 = 67,108,864 B
    short* zpage   = (short*)((char*)d_ws + 4096 + 7077888 + 67108864); // 256 B zeros

    hipMemsetAsync(zpage, 0, 256, stream);
    k_style<<<BATCH, 128, 0, stream>>>(s, aw, ab, style_m);
    k_wmod<<<BATCH * CO, 64, 0, stream>>>(w, style_m, wmodT);
    k_xt<<<BATCH * 1024, 256, 0, stream>>>(x, xT);
    k_conv<<<BATCH * 128, 512, 0, stream>>>(xT, wmodT, bb, out, zpage);
}